// Round 15
// baseline (568.516 us; speedup 1.0000x reference)
//
#include <hip/hip_runtime.h>
#include <hip/hip_bf16.h>

typedef __attribute__((ext_vector_type(4))) float f32x4;
typedef __attribute__((ext_vector_type(2))) float f32x2;
typedef __attribute__((ext_vector_type(8))) short s16x8;
typedef __attribute__((ext_vector_type(4))) short s16x4;
typedef __attribute__((ext_vector_type(4))) unsigned short u16x4;

#define HW 512
#define NSLICE 128  // 16 b * 8 ch

union B4 { s16x4 v; __hip_bfloat16 e[4]; };

// ---------------------------------------------------------------------------
// Kernel 1: fused conv1x1 + dw3x3, barrier-free main loop (R15).
// R12's private-compute idea WITHOUT the 144-reg x-window cache (that
// spilled): each o-pair's conv window is read directly from the LDS x tile.
// Barriers: 1 (xs publish) + 1 (colsq) — vs R13's 6 store-draining barriers.
// 46 KB LDS -> 3 blocks/CU. Chunked output layout [slice][chn][row][32 bf16]
// unchanged; stores identical to R13 (verified).
// ---------------------------------------------------------------------------
__global__ __launch_bounds__(256) void qkv_fused(
    const float* __restrict__ x, const float* __restrict__ wqkv,
    const float* __restrict__ wdw,
    __hip_bfloat16* __restrict__ qT, __hip_bfloat16* __restrict__ kT,
    __hip_bfloat16* __restrict__ vS,
    float* __restrict__ qss, float* __restrict__ kss)
{
  const int b = blockIdx.y;
  const int tile = blockIdx.x;
  const int h0 = (tile >> 4) * 32;
  const int w0 = (tile & 15) * 32;
  const int tid = threadIdx.x;

  __shared__ float xs[8][1156];        // 37 KB x tile with halo
  __shared__ float colsq[4][16][32];   // 8 KB ssq partials
  __shared__ float wq_s[24][8];
  __shared__ float wd_s[24][9];

  if (tid < 192) wq_s[tid >> 3][tid & 7] = wqkv[tid];
  if (tid < 216) wd_s[tid / 9][tid % 9] = wdw[tid];

  #pragma unroll
  for (int p = 0; p < 5; ++p) {
    int i = tid + p * 256;
    if (i < 1156) {
      int ih = h0 - 1 + i / 34, iw = w0 - 1 + i % 34;
      bool ok = (ih >= 0 && ih < HW && iw >= 0 && iw < HW);
      #pragma unroll
      for (int c = 0; c < 8; ++c)
        xs[c][i] = ok ? x[((size_t)(b * 8 + c) * HW + ih) * HW + iw] : 0.f;
    }
  }
  __syncthreads();  // B1: x + weights visible; xs read-only hereafter

  const int tw = tid & 31;   // w column in tile
  const int th = tid >> 5;   // h strip (4 rows)
  const int lane = tid & 63;
  const int wv = tid >> 6;
  const int base_i = 4 * th * 34 + tw;   // xs index of window origin

  for (int pr = 0; pr < 12; ++pr) {      // o-pair index; o = 2*pr
    const int o = pr * 2;
    // conv1x1 into private 6x3 windows for o, o+1 (reads xs directly)
    float t0[6][3], t1[6][3];
    #pragma unroll
    for (int wr = 0; wr < 6; ++wr)
      #pragma unroll
      for (int wc = 0; wc < 3; ++wc) { t0[wr][wc] = 0.f; t1[wr][wc] = 0.f; }
    #pragma unroll
    for (int c = 0; c < 8; ++c) {
      const float wc0 = wq_s[o][c];
      const float wc1 = wq_s[o + 1][c];
      #pragma unroll
      for (int wr = 0; wr < 6; ++wr) {
        #pragma unroll
        for (int wc = 0; wc < 3; ++wc) {
          float xv = xs[c][base_i + wr * 34 + wc];
          t0[wr][wc] += xv * wc0;
          t1[wr][wc] += xv * wc1;
        }
      }
    }
    // depthwise 3x3: 4 outputs per channel
    float o0[4], o1[4];
    #pragma unroll
    for (int r = 0; r < 4; ++r) { o0[r] = 0.f; o1[r] = 0.f; }
    #pragma unroll
    for (int di = 0; di < 3; ++di)
      #pragma unroll
      for (int dj = 0; dj < 3; ++dj) {
        const float wd0 = wd_s[o][di * 3 + dj];
        const float wd1 = wd_s[o + 1][di * 3 + dj];
        #pragma unroll
        for (int r = 0; r < 4; ++r) {
          o0[r] += t0[r + di][dj] * wd0;
          o1[r] += t1[r + di][dj] * wd1;
        }
      }
    if (pr < 8) {   // q (pr<4) or k
      float s0 = o0[0]*o0[0] + o0[1]*o0[1] + o0[2]*o0[2] + o0[3]*o0[3];
      float s1 = o1[0]*o1[0] + o1[1]*o1[1] + o1[2]*o1[2] + o1[3]*o1[3];
      s0 += __shfl_xor(s0, 32);
      s1 += __shfl_xor(s1, 32);
      if (lane < 32) {
        colsq[wv][pr * 2][tw] = s0;
        colsq[wv][pr * 2 + 1][tw] = s1;
      }
      B4 u0, u1;
      #pragma unroll
      for (int r = 0; r < 4; ++r) {
        u0.e[r] = __float2bfloat16(o0[r]);
        u1.e[r] = __float2bfloat16(o1[r]);
      }
      __hip_bfloat16* base = (pr < 4) ? qT : kT;
      const int oc = (pr & 3) * 2;     // channel within q or k
      size_t a0i = (size_t)(b * 8 + oc) * HW * HW
                 + (size_t)(h0 >> 5) * HW * 32 + (size_t)(w0 + tw) * 32 + 4 * th;
      *(s16x4*)(base + a0i) = u0.v;
      *(s16x4*)(base + a0i + (size_t)HW * HW) = u1.v;
    } else {        // v
      const int oc = (pr & 3) * 2;
      __hip_bfloat16* vb0 = vS + (size_t)(b * 8 + oc) * HW * HW
                          + (size_t)(w0 >> 5) * HW * 32 + (size_t)(h0 + 4 * th) * 32 + tw;
      __hip_bfloat16* vb1 = vb0 + (size_t)HW * HW;
      #pragma unroll
      for (int r = 0; r < 4; ++r) {
        vb0[r * 32] = __float2bfloat16(o0[r]);
        vb1[r * 32] = __float2bfloat16(o1[r]);
      }
    }
  }
  __syncthreads();  // B2: colsq visible
  #pragma unroll
  for (int k = 0; k < 2; ++k) {
    int idx = tid + k * 256;          // 512 (oi,w) slots
    int oi = idx >> 5, w = idx & 31;
    float s = colsq[0][oi][w] + colsq[1][oi][w] + colsq[2][oi][w] + colsq[3][oi][w];
    float* dst = (oi < 8 ? qss : kss) + (size_t)(b * 8 + (oi & 7)) * HW + w0 + w;
    atomicAdd(dst, s);
  }
}

// ---------------------------------------------------------------------------
// Kernel 2: per-slice attention — R13 VERBATIM (measured 153 us, VGPR 92,
// no spill): 8 waves, BM=64, chunked layout, Q in LDS (1040B rows),
// K/V via asm-pinned 4-set vmcnt pipeline, (512,1).
// ---------------------------------------------------------------------------
#define QROW 1040         // 1024B Q row + 16B pad (bank spread)
#define LDS_QP   0        // Q staging 64*1040=66560; P [64][1024] reuses [0,65536)
#define OFF_RMAX 66560    // [64][8] f32
#define OFF_RSUM 68608    // [64][8] f32
#define OFF_RMAXF 70656   // [64] f32
#define OFF_RSINV 70912   // [64] f32
#define OFF_SQ   71168    // [64] f32
#define OFF_SK   71424    // [512] f32
#define ATTN_LDS_SIZE 73472

#define GL4(D, VOFF, BASE) \
  asm volatile("global_load_dwordx4 %0, %1, %2 offset:0"    : "=v"(D[0]) : "v"(VOFF), "s"(BASE)); \
  asm volatile("global_load_dwordx4 %0, %1, %2 offset:1024" : "=v"(D[1]) : "v"(VOFF), "s"(BASE)); \
  asm volatile("global_load_dwordx4 %0, %1, %2 offset:2048" : "=v"(D[2]) : "v"(VOFF), "s"(BASE)); \
  asm volatile("global_load_dwordx4 %0, %1, %2 offset:3072" : "=v"(D[3]) : "v"(VOFF), "s"(BASE));

#define LOADSETK(BF, CHN) { \
  const char* bk_ = ks + (size_t)(CHN) * 32768; \
  GL4(BF, voffK, bk_) }

#define LOADSETV(VF, CHN) { \
  const char* bv_ = vs + (size_t)(CHN) * 32768; \
  GL4(VF, voffK, bv_) }

#define WAITV(N) \
  asm volatile("s_waitcnt vmcnt(" #N ")"); \
  __builtin_amdgcn_sched_barrier(0);

#define LDSQ(QF, S) { \
    const int cq_ = (S) * 64 + klo; \
    _Pragma("unroll") for (int m_ = 0; m_ < 4; ++m_) \
      QF[m_] = *(const s16x8*)(ldsQ + (m_ * 16 + arow) * QROW + cq_); }

#define LOADP(AF, S) { \
    const int cbp_ = (S) * 64 + klo; \
    _Pragma("unroll") for (int m_ = 0; m_ < 4; ++m_) { \
      const int row_ = m_ * 16 + arow; \
      AF[m_] = *(const s16x8*)(ldsP + row_ * 1024 + (cbp_ ^ ((row_ & 7) << 4))); } }
#define MFMA16(AF, BF, ACC) { \
    _Pragma("unroll") for (int m_ = 0; m_ < 4; ++m_) \
      _Pragma("unroll") for (int n_ = 0; n_ < 4; ++n_) \
        ACC[m_][n_] = __builtin_amdgcn_mfma_f32_16x16x32_bf16(AF[m_], BF[n_], ACC[m_][n_], 0, 0, 0); }

__global__ __launch_bounds__(512, 1) void attn_kernel(
    const __hip_bfloat16* __restrict__ qT, const __hip_bfloat16* __restrict__ kT,
    const __hip_bfloat16* __restrict__ vS, __hip_bfloat16* __restrict__ Obuf,
    const float* __restrict__ qss, const float* __restrict__ kss,
    const float* __restrict__ temp)
{
  extern __shared__ char smem[];
  char* ldsQ = smem + LDS_QP;
  char* ldsP = smem + LDS_QP;
  float* red_max  = (float*)(smem + OFF_RMAX);
  float* red_sum  = (float*)(smem + OFF_RSUM);
  float* red_maxf = (float*)(smem + OFF_RMAXF);
  float* rsinv    = (float*)(smem + OFF_RSINV);
  float* sq_l     = (float*)(smem + OFF_SQ);
  float* sk_l     = (float*)(smem + OFF_SK);

  const int tid = threadIdx.x;
  const int lane = tid & 63;
  const int wv = tid >> 6;
  const int p = blockIdx.x;
  const int slice = (p & 7) + 8 * (p >> 6);
  const int rblk = (p >> 3) & 7;
  const int w0 = rblk * 64;
  const size_t sbase = (size_t)slice * HW * HW;
  const char* qs = (const char*)(qT + sbase);
  const char* ks = (const char*)(kT + sbase);
  const char* vs = (const char*)(vS + sbase);

  const int klo = (lane >> 4) << 4;
  const int arow = lane & 15;
  const int voffK = (wv * 64 + arow) * 64 + klo;

  {
    const int r = tid >> 3;
    const int seg = tid & 7;
    #pragma unroll
    for (int i = 0; i < 8; ++i) {
      const int chn_i = seg * 2 + (i >> 2);
      s16x8 v = *(const s16x8*)(qs + (size_t)chn_i * 32768 + (size_t)(w0 + r) * 64 + (i & 3) * 16);
      *(s16x8*)(ldsQ + r * QROW + seg * 128 + i * 16) = v;
    }
  }
  const float tmp = temp[(slice & 7) >> 1];
  if (tid < 64) sq_l[tid] = tmp / fmaxf(sqrtf(qss[(size_t)slice * HW + w0 + tid]), 1e-12f);
  sk_l[tid] = 1.f / fmaxf(sqrtf(kss[(size_t)slice * HW + tid]), 1e-12f);
  __syncthreads();

  f32x4 acc[4][4];
  #pragma unroll
  for (int m = 0; m < 4; ++m)
    #pragma unroll
    for (int n = 0; n < 4; ++n) acc[m][n] = (f32x4){0.f, 0.f, 0.f, 0.f};
  __builtin_amdgcn_sched_barrier(0);

  s16x8 bfA[4], bfB[4], bfC[4], bfD[4];
  LOADSETK(bfA, 0)
  LOADSETK(bfB, 1)
  LOADSETK(bfC, 2)
  LOADSETK(bfD, 3)

  #pragma unroll
  for (int g = 0; g < 3; ++g) {
    { s16x8 qf[4]; LDSQ(qf, 4 * g + 0) WAITV(12) MFMA16(qf, bfA, acc) } LOADSETK(bfA, 4 * g + 4)
    { s16x8 qf[4]; LDSQ(qf, 4 * g + 1) WAITV(12) MFMA16(qf, bfB, acc) } LOADSETK(bfB, 4 * g + 5)
    { s16x8 qf[4]; LDSQ(qf, 4 * g + 2) WAITV(12) MFMA16(qf, bfC, acc) } LOADSETK(bfC, 4 * g + 6)
    { s16x8 qf[4]; LDSQ(qf, 4 * g + 3) WAITV(12) MFMA16(qf, bfD, acc) } LOADSETK(bfD, 4 * g + 7)
  }
  { s16x8 qf[4]; LDSQ(qf, 12) WAITV(12) MFMA16(qf, bfA, acc) }
  { s16x8 qf[4]; LDSQ(qf, 13) WAITV(8)  MFMA16(qf, bfB, acc) }
  { s16x8 qf[4]; LDSQ(qf, 14) WAITV(4)  MFMA16(qf, bfC, acc) }
  { s16x8 qf[4]; LDSQ(qf, 15) WAITV(0)  MFMA16(qf, bfD, acc) }
  __syncthreads();

  float srow[4][4], scol[4];
  #pragma unroll
  for (int m = 0; m < 4; ++m)
    #pragma unroll
    for (int r = 0; r < 4; ++r)
      srow[m][r] = sq_l[m * 16 + ((lane >> 4) << 2) + r];
  #pragma unroll
  for (int n = 0; n < 4; ++n) scol[n] = sk_l[wv * 64 + n * 16 + (lane & 15)];

  float rmax[4][4];
  #pragma unroll
  for (int m = 0; m < 4; ++m)
    #pragma unroll
    for (int r = 0; r < 4; ++r) {
      float mx = -1e30f;
      #pragma unroll
      for (int n = 0; n < 4; ++n) {
        float v = acc[m][n][r] * srow[m][r] * scol[n];
        acc[m][n][r] = v;
        mx = fmaxf(mx, v);
      }
      mx = fmaxf(mx, __shfl_xor(mx, 1));
      mx = fmaxf(mx, __shfl_xor(mx, 2));
      mx = fmaxf(mx, __shfl_xor(mx, 4));
      mx = fmaxf(mx, __shfl_xor(mx, 8));
      rmax[m][r] = mx;
    }
  if ((lane & 15) == 0) {
    #pragma unroll
    for (int m = 0; m < 4; ++m)
      #pragma unroll
      for (int r = 0; r < 4; ++r)
        red_max[(m * 16 + ((lane >> 4) << 2) + r) * 8 + wv] = rmax[m][r];
  }
  __syncthreads();
  if (tid < 64) {
    float mx = red_max[tid * 8];
    #pragma unroll
    for (int g = 1; g < 8; ++g) mx = fmaxf(mx, red_max[tid * 8 + g]);
    red_maxf[tid] = mx;
  }
  __syncthreads();

  float gmax[4][4];
  #pragma unroll
  for (int m = 0; m < 4; ++m)
    #pragma unroll
    for (int r = 0; r < 4; ++r)
      gmax[m][r] = red_maxf[m * 16 + ((lane >> 4) << 2) + r];

  s16x8 vfA[4], vfB[4], vfC[4], vfD[4];
  LOADSETV(vfA, 0)
  LOADSETV(vfB, 1)
  LOADSETV(vfC, 2)
  LOADSETV(vfD, 3)

  float rs[4][4];
  #pragma unroll
  for (int m = 0; m < 4; ++m)
    #pragma unroll
    for (int r = 0; r < 4; ++r) rs[m][r] = 0.f;
  #pragma unroll
  for (int m = 0; m < 4; ++m)
    #pragma unroll
    for (int n = 0; n < 4; ++n)
      #pragma unroll
      for (int r = 0; r < 4; ++r) {
        int row = m * 16 + ((lane >> 4) << 2) + r;
        int col = wv * 64 + n * 16 + (lane & 15);
        float pv = __expf(acc[m][n][r] - gmax[m][r]);
        rs[m][r] += pv;
        *(__hip_bfloat16*)(ldsP + row * 1024 + ((col * 2) ^ ((row & 7) << 4))) =
            __float2bfloat16(pv);
      }
  #pragma unroll
  for (int m = 0; m < 4; ++m)
    #pragma unroll
    for (int r = 0; r < 4; ++r) {
      float s = rs[m][r];
      s += __shfl_xor(s, 1);
      s += __shfl_xor(s, 2);
      s += __shfl_xor(s, 4);
      s += __shfl_xor(s, 8);
      if ((lane & 15) == 0)
        red_sum[(m * 16 + ((lane >> 4) << 2) + r) * 8 + wv] = s;
    }
  __syncthreads();
  if (tid < 64) {
    float s = 0.f;
    #pragma unroll
    for (int g = 0; g < 8; ++g) s += red_sum[tid * 8 + g];
    rsinv[tid] = 1.f / s;
  }

  f32x4 acc2[4][4];
  #pragma unroll
  for (int m = 0; m < 4; ++m)
    #pragma unroll
    for (int n = 0; n < 4; ++n) acc2[m][n] = (f32x4){0.f, 0.f, 0.f, 0.f};

  #pragma unroll
  for (int g = 0; g < 3; ++g) {
    { s16x8 pf[4]; LOADP(pf, 4 * g + 0) WAITV(12) MFMA16(pf, vfA, acc2) } LOADSETV(vfA, 4 * g + 4)
    { s16x8 pf[4]; LOADP(pf, 4 * g + 1) WAITV(12) MFMA16(pf, vfB, acc2) } LOADSETV(vfB, 4 * g + 5)
    { s16x8 pf[4]; LOADP(pf, 4 * g + 2) WAITV(12) MFMA16(pf, vfC, acc2) } LOADSETV(vfC, 4 * g + 6)
    { s16x8 pf[4]; LOADP(pf, 4 * g + 3) WAITV(12) MFMA16(pf, vfD, acc2) } LOADSETV(vfD, 4 * g + 7)
  }
  { s16x8 pf[4]; LOADP(pf, 12) WAITV(12) MFMA16(pf, vfA, acc2) }
  { s16x8 pf[4]; LOADP(pf, 13) WAITV(8)  MFMA16(pf, vfB, acc2) }
  { s16x8 pf[4]; LOADP(pf, 14) WAITV(4)  MFMA16(pf, vfC, acc2) }
  { s16x8 pf[4]; LOADP(pf, 15) WAITV(0)  MFMA16(pf, vfD, acc2) }
  __syncthreads();

  float rinv[4][4];
  #pragma unroll
  for (int m = 0; m < 4; ++m)
    #pragma unroll
    for (int r = 0; r < 4; ++r)
      rinv[m][r] = rsinv[m * 16 + ((lane >> 4) << 2) + r];

  char* ldsO = ldsP + wv * 8192;
  #pragma unroll
  for (int m = 0; m < 4; ++m)
    #pragma unroll
    for (int n = 0; n < 4; ++n)
      #pragma unroll
      for (int r = 0; r < 4; ++r) {
        int row = m * 16 + ((lane >> 4) << 2) + r;
        int col = n * 16 + (lane & 15);
        *(__hip_bfloat16*)(ldsO + row * 128 + col * 2) =
            __float2bfloat16(acc2[m][n][r] * rinv[m][r]);
      }
  __syncthreads();
  __hip_bfloat16* ob = Obuf + sbase + (size_t)w0 * HW + wv * 64;
  #pragma unroll
  for (int it = 0; it < 8; ++it) {
    int row = it * 8 + (lane >> 3);
    int c = (lane & 7) << 4;
    s16x8 v = *(const s16x8*)(ldsO + row * 128 + c);
    *(s16x8*)((char*)ob + (size_t)row * 1024 + c) = v;
  }
}

// ---------------------------------------------------------------------------
// Kernel 3: out[b][j][h][w] = sum_o wout[j][o] * O[b][o][w][h]  (unchanged)
// ---------------------------------------------------------------------------
__global__ __launch_bounds__(256) void proj_kernel(
    const __hip_bfloat16* __restrict__ Obuf, const float* __restrict__ wout,
    float* __restrict__ out)
{
  const int b = blockIdx.y;
  const int t = blockIdx.x;
  const int h0 = (t >> 5) * 64;
  const int w0 = (t & 31) * 16;
  const int tid = threadIdx.x;
  __shared__ float os[8][16][65];
  __shared__ float wo_s[64];
  if (tid < 64) wo_s[tid] = wout[tid];
  {
    int r = tid >> 4;
    int c4 = (tid & 15) * 4;
    #pragma unroll
    for (int o = 0; o < 8; ++o) {
      const __hip_bfloat16* p = Obuf + ((size_t)(b * 8 + o) * HW + w0 + r) * HW + h0 + c4;
      u16x4 v = *(const u16x4*)p;
      #pragma unroll
      for (int i = 0; i < 4; ++i)
        os[o][r][c4 + i] = __uint_as_float((unsigned)v[i] << 16);
    }
  }
  __syncthreads();
  const int w = tid & 15;
  #pragma unroll
  for (int ih = 0; ih < 4; ++ih) {
    int h = ih * 16 + (tid >> 4);
    float ov[8];
    #pragma unroll
    for (int o = 0; o < 8; ++o) ov[o] = os[o][w][h];
    #pragma unroll
    for (int jo = 0; jo < 8; ++jo) {
      float a = 0.f;
      #pragma unroll
      for (int o = 0; o < 8; ++o) a += ov[o] * wo_s[jo * 8 + o];
      out[((size_t)(b * 8 + jo) * HW + h0 + h) * HW + w0 + w] = a;
    }
  }
}

extern "C" void kernel_launch(void* const* d_in, const int* in_sizes, int n_in,
                              void* d_out, int out_size, void* d_ws, size_t ws_size,
                              hipStream_t stream) {
  (void)in_sizes; (void)n_in; (void)out_size; (void)ws_size;
  const float* x    = (const float*)d_in[0];
  const float* wqkv = (const float*)d_in[1];
  const float* wdw  = (const float*)d_in[2];
  const float* wout = (const float*)d_in[3];
  const float* temp = (const float*)d_in[4];
  float* out = (float*)d_out;

  char* ws = (char*)d_ws;
  const size_t plane = (size_t)NSLICE * HW * HW * 2;  // 64 MiB bf16 plane
  __hip_bfloat16* qT = (__hip_bfloat16*)(ws);
  __hip_bfloat16* kT = (__hip_bfloat16*)(ws + plane);
  __hip_bfloat16* vS = (__hip_bfloat16*)(ws + 2 * plane);
  __hip_bfloat16* Ob = (__hip_bfloat16*)(ws + 3 * plane);
  float* qss = (float*)(ws + 4 * plane);
  float* kss = (float*)(ws + 4 * plane + (size_t)NSLICE * HW * 4);

  hipMemsetAsync(qss, 0, 2 * (size_t)NSLICE * HW * 4, stream);
  qkv_fused<<<dim3(256, 16), 256, 0, stream>>>(x, wqkv, wdw, qT, kT, vS, qss, kss);
  hipFuncSetAttribute((const void*)attn_kernel,
                      hipFuncAttributeMaxDynamicSharedMemorySize, ATTN_LDS_SIZE);
  attn_kernel<<<dim3(1024), 512, ATTN_LDS_SIZE, stream>>>(qT, kT, vS, Ob, qss, kss, temp);
  proj_kernel<<<dim3(256, 16), 256, 0, stream>>>(Ob, wout, out);
}

// Round 16
// 327.932 us; speedup vs baseline: 1.7336x; 1.7336x over previous
//
#include <hip/hip_runtime.h>
#include <hip/hip_bf16.h>

typedef __attribute__((ext_vector_type(4))) float f32x4;
typedef __attribute__((ext_vector_type(2))) float f32x2;
typedef __attribute__((ext_vector_type(8))) short s16x8;
typedef __attribute__((ext_vector_type(4))) short s16x4;
typedef __attribute__((ext_vector_type(4))) unsigned short u16x4;

#define HW 512
#define NSLICE 128  // 16 b * 8 ch

union B4 { s16x4 v; __hip_bfloat16 e[4]; };

// ---------------------------------------------------------------------------
// Kernel 1: fused conv1x1 + dw3x3 — R13 VERBATIM (ts-staged, direct stores,
// 42.9 KB LDS, 3 blocks/CU; measured best). Chunked layout
// [slice][chn][row][32 bf16]; qT/kT: chn=h/32,row=w ; vS: chn=v/32,row=h.
// ---------------------------------------------------------------------------
__global__ __launch_bounds__(256) void qkv_fused(
    const float* __restrict__ x, const float* __restrict__ wqkv,
    const float* __restrict__ wdw,
    __hip_bfloat16* __restrict__ qT, __hip_bfloat16* __restrict__ kT,
    __hip_bfloat16* __restrict__ vS,
    float* __restrict__ qss, float* __restrict__ kss)
{
  const int b = blockIdx.y;
  const int tile = blockIdx.x;
  const int h0 = (tile >> 4) * 32;
  const int w0 = (tile & 15) * 32;
  const int tid = threadIdx.x;

  __shared__ float ts[4][1156][2];
  __shared__ float colsq[4][8][32];
  __shared__ float wq_s[24][8];
  __shared__ float wd_s[24][12];

  if (tid < 192) wq_s[tid >> 3][tid & 7] = wqkv[tid];
  if (tid < 216) wd_s[tid / 9][tid % 9] = wdw[tid];

  float xr[5][8];
  #pragma unroll
  for (int p = 0; p < 5; ++p) {
    int i = tid + p * 256;
    if (i < 1156) {
      int ih = h0 - 1 + i / 34, iw = w0 - 1 + i % 34;
      bool ok = (ih >= 0 && ih < HW && iw >= 0 && iw < HW);
      #pragma unroll
      for (int c = 0; c < 8; ++c)
        xr[p][c] = ok ? x[((size_t)(b * 8 + c) * HW + ih) * HW + iw] : 0.f;
    }
  }
  __syncthreads();

  const int tw = tid & 31;
  const int th = tid >> 5;
  const int lane = tid & 63;
  const int wv = tid >> 6;

  #pragma unroll
  for (int g = 0; g < 3; ++g) {
    #pragma unroll
    for (int p = 0; p < 5; ++p) {
      int i = tid + p * 256;
      if (i < 1156) {
        #pragma unroll
        for (int op = 0; op < 4; ++op) {
          const int o = g * 8 + op * 2;
          float a0 = 0.f, a1 = 0.f;
          #pragma unroll
          for (int c = 0; c < 8; ++c) {
            a0 += xr[p][c] * wq_s[o][c];
            a1 += xr[p][c] * wq_s[o + 1][c];
          }
          ts[op][i][0] = a0;
          ts[op][i][1] = a1;
        }
      }
    }
    __syncthreads();

    #pragma unroll
    for (int op = 0; op < 4; ++op) {
      const int o = g * 8 + op * 2;
      float w2[6][3][2];
      #pragma unroll
      for (int r = 0; r < 6; ++r)
        #pragma unroll
        for (int c = 0; c < 3; ++c) {
          f32x2 v = *(const f32x2*)&ts[op][(4 * th + r) * 34 + tw + c][0];
          w2[r][c][0] = v[0];
          w2[r][c][1] = v[1];
        }
      float o0[4], o1[4];
      #pragma unroll
      for (int r = 0; r < 4; ++r) { o0[r] = 0.f; o1[r] = 0.f; }
      #pragma unroll
      for (int di = 0; di < 3; ++di)
        #pragma unroll
        for (int dj = 0; dj < 3; ++dj) {
          const float wd0 = wd_s[o][di * 3 + dj];
          const float wd1 = wd_s[o + 1][di * 3 + dj];
          #pragma unroll
          for (int r = 0; r < 4; ++r) {
            o0[r] += w2[r + di][dj][0] * wd0;
            o1[r] += w2[r + di][dj][1] * wd1;
          }
        }
      if (g < 2) {
        float s0 = o0[0]*o0[0] + o0[1]*o0[1] + o0[2]*o0[2] + o0[3]*o0[3];
        float s1 = o1[0]*o1[0] + o1[1]*o1[1] + o1[2]*o1[2] + o1[3]*o1[3];
        s0 += __shfl_xor(s0, 32);
        s1 += __shfl_xor(s1, 32);
        if (lane < 32) {
          colsq[wv][op * 2][tw] = s0;
          colsq[wv][op * 2 + 1][tw] = s1;
        }
        B4 u0, u1;
        #pragma unroll
        for (int r = 0; r < 4; ++r) {
          u0.e[r] = __float2bfloat16(o0[r]);
          u1.e[r] = __float2bfloat16(o1[r]);
        }
        __hip_bfloat16* base = (g == 0) ? qT : kT;
        size_t a0i = (size_t)(b * 8 + op * 2) * HW * HW
                   + (size_t)(h0 >> 5) * HW * 32 + (size_t)(w0 + tw) * 32 + 4 * th;
        *(s16x4*)(base + a0i) = u0.v;
        *(s16x4*)(base + a0i + (size_t)HW * HW) = u1.v;
      } else {
        __hip_bfloat16* vb0 = vS + (size_t)(b * 8 + op * 2) * HW * HW
                            + (size_t)(w0 >> 5) * HW * 32 + (size_t)(h0 + 4 * th) * 32 + tw;
        __hip_bfloat16* vb1 = vb0 + (size_t)HW * HW;
        #pragma unroll
        for (int r = 0; r < 4; ++r) {
          vb0[r * 32] = __float2bfloat16(o0[r]);
          vb1[r * 32] = __float2bfloat16(o1[r]);
        }
      }
    }
    __syncthreads();

    if (g < 2) {
      const int o = tid >> 5, w = tid & 31;
      float s = colsq[0][o][w] + colsq[1][o][w] + colsq[2][o][w] + colsq[3][o][w];
      float* dst = (g == 0 ? qss : kss) + (size_t)(b * 8 + o) * HW + w0 + w;
      atomicAdd(dst, s);
    }
  }
}

// ---------------------------------------------------------------------------
// Kernel 2: per-slice attention, 16 waves (1024 thr), BM=64, 32-col n-stripe
// per wave: acc = 4m x 2n x 4 = 32 regs (half of R13) -> peak live ~110,
// (1024,4) => 4 waves/SIMD (2x R13 TLP) with UNCHANGED per-CU K/V traffic.
// Q deduped in LDS; K/V via asm-pinned depth-4 pipeline (2 loads/set,
// vmcnt(6)). Chunked layout as before.
// ---------------------------------------------------------------------------
#define QROW 1040
#define LDS_QP   0        // Q 64*1040=66560 / P [64][1024] reuse [0,65536)
#define OFF_RMAX 66560    // [64][16] f32
#define OFF_RSUM 70656    // [64][16] f32
#define OFF_RMAXF 74752   // [64] f32
#define OFF_RSINV 75008   // [64] f32
#define OFF_SQ   75264    // [64] f32
#define OFF_SK   75520    // [512] f32
#define ATTN_LDS_SIZE 77568

#define GL2(D, VOFF, BASE) \
  asm volatile("global_load_dwordx4 %0, %1, %2 offset:0"    : "=v"(D[0]) : "v"(VOFF), "s"(BASE)); \
  asm volatile("global_load_dwordx4 %0, %1, %2 offset:1024" : "=v"(D[1]) : "v"(VOFF), "s"(BASE));

#define LOADSETK(BF, CHN) { \
  const char* bk_ = ks + (size_t)(CHN) * 32768; \
  GL2(BF, voffK, bk_) }

#define LOADSETV(VF, CHN) { \
  const char* bv_ = vs + (size_t)(CHN) * 32768; \
  GL2(VF, voffK, bv_) }

#define WAITV(N) \
  asm volatile("s_waitcnt vmcnt(" #N ")"); \
  __builtin_amdgcn_sched_barrier(0);

#define LDSQ(QF, S) { \
    const int cq_ = (S) * 64 + klo; \
    _Pragma("unroll") for (int m_ = 0; m_ < 4; ++m_) \
      QF[m_] = *(const s16x8*)(ldsQ + (m_ * 16 + arow) * QROW + cq_); }

#define LOADP(AF, S) { \
    const int cbp_ = (S) * 64 + klo; \
    _Pragma("unroll") for (int m_ = 0; m_ < 4; ++m_) { \
      const int row_ = m_ * 16 + arow; \
      AF[m_] = *(const s16x8*)(ldsP + row_ * 1024 + (cbp_ ^ ((row_ & 7) << 4))); } }

#define MFMA8(AF, BF, ACC) { \
    _Pragma("unroll") for (int m_ = 0; m_ < 4; ++m_) \
      _Pragma("unroll") for (int n_ = 0; n_ < 2; ++n_) \
        ACC[m_][n_] = __builtin_amdgcn_mfma_f32_16x16x32_bf16(AF[m_], BF[n_], ACC[m_][n_], 0, 0, 0); }

__global__ __launch_bounds__(1024, 4) void attn_kernel(
    const __hip_bfloat16* __restrict__ qT, const __hip_bfloat16* __restrict__ kT,
    const __hip_bfloat16* __restrict__ vS, __hip_bfloat16* __restrict__ Obuf,
    const float* __restrict__ qss, const float* __restrict__ kss,
    const float* __restrict__ temp)
{
  extern __shared__ char smem[];
  char* ldsQ = smem + LDS_QP;
  char* ldsP = smem + LDS_QP;
  float* red_max  = (float*)(smem + OFF_RMAX);
  float* red_sum  = (float*)(smem + OFF_RSUM);
  float* red_maxf = (float*)(smem + OFF_RMAXF);
  float* rsinv    = (float*)(smem + OFF_RSINV);
  float* sq_l     = (float*)(smem + OFF_SQ);
  float* sk_l     = (float*)(smem + OFF_SK);

  const int tid = threadIdx.x;
  const int lane = tid & 63;
  const int wv = tid >> 6;          // 0..15
  const int p = blockIdx.x;
  // XCD swizzle: 8 row-blocks of one slice share an XCD
  const int slice = (p & 7) + 8 * (p >> 6);
  const int rblk = (p >> 3) & 7;
  const int w0 = rblk * 64;
  const size_t sbase = (size_t)slice * HW * HW;
  const char* qs = (const char*)(qT + sbase);
  const char* ks = (const char*)(kT + sbase);
  const char* vs = (const char*)(vS + sbase);

  const int klo = (lane >> 4) << 4;   // 16B k-slot
  const int arow = lane & 15;
  const int voffK = (wv * 32 + arow) * 64 + klo;  // + n*1024 imm (K and V)

  // ---- stage Q tile (64 rows x 1KB) into LDS ----
  {
    const int r = tid >> 4;          // 0..63
    const int seg = tid & 15;        // 64B segment = one chn's contribution
    const char* src = qs + (size_t)seg * 32768 + (size_t)(w0 + r) * 64;
    char* dst = ldsQ + r * QROW + seg * 64;
    #pragma unroll
    for (int i = 0; i < 4; ++i)
      *(s16x8*)(dst + i * 16) = *(const s16x8*)(src + i * 16);
  }
  const float tmp = temp[(slice & 7) >> 1];
  if (tid < 64) sq_l[tid] = tmp / fmaxf(sqrtf(qss[(size_t)slice * HW + w0 + tid]), 1e-12f);
  if (tid < 512) sk_l[tid] = 1.f / fmaxf(sqrtf(kss[(size_t)slice * HW + tid]), 1e-12f);
  __syncthreads();  // Q + scales visible

  f32x4 acc[4][2];
  #pragma unroll
  for (int m = 0; m < 4; ++m)
    #pragma unroll
    for (int n = 0; n < 2; ++n) acc[m][n] = (f32x4){0.f, 0.f, 0.f, 0.f};
  __builtin_amdgcn_sched_barrier(0);

  // ---- phase 1: S = Q K^T; Q from LDS, K via depth-4 asm pipeline ----
  s16x8 bfA[2], bfB[2], bfC[2], bfD[2];
  LOADSETK(bfA, 0)
  LOADSETK(bfB, 1)
  LOADSETK(bfC, 2)
  LOADSETK(bfD, 3)

  #pragma unroll
  for (int g = 0; g < 3; ++g) {
    { s16x8 qf[4]; LDSQ(qf, 4 * g + 0) WAITV(6) MFMA8(qf, bfA, acc) } LOADSETK(bfA, 4 * g + 4)
    { s16x8 qf[4]; LDSQ(qf, 4 * g + 1) WAITV(6) MFMA8(qf, bfB, acc) } LOADSETK(bfB, 4 * g + 5)
    { s16x8 qf[4]; LDSQ(qf, 4 * g + 2) WAITV(6) MFMA8(qf, bfC, acc) } LOADSETK(bfC, 4 * g + 6)
    { s16x8 qf[4]; LDSQ(qf, 4 * g + 3) WAITV(6) MFMA8(qf, bfD, acc) } LOADSETK(bfD, 4 * g + 7)
  }
  { s16x8 qf[4]; LDSQ(qf, 12) WAITV(6) MFMA8(qf, bfA, acc) }
  { s16x8 qf[4]; LDSQ(qf, 13) WAITV(4) MFMA8(qf, bfB, acc) }
  { s16x8 qf[4]; LDSQ(qf, 14) WAITV(2) MFMA8(qf, bfC, acc) }
  { s16x8 qf[4]; LDSQ(qf, 15) WAITV(0) MFMA8(qf, bfD, acc) }
  __syncthreads();  // all waves done reading Q; P may overwrite

  // ---- softmax over v (rows w) ----
  float srow[4][4], scol[2];
  #pragma unroll
  for (int m = 0; m < 4; ++m)
    #pragma unroll
    for (int r = 0; r < 4; ++r)
      srow[m][r] = sq_l[m * 16 + ((lane >> 4) << 2) + r];
  #pragma unroll
  for (int n = 0; n < 2; ++n) scol[n] = sk_l[wv * 32 + n * 16 + (lane & 15)];

  float rmax[4][4];
  #pragma unroll
  for (int m = 0; m < 4; ++m)
    #pragma unroll
    for (int r = 0; r < 4; ++r) {
      float mx = -1e30f;
      #pragma unroll
      for (int n = 0; n < 2; ++n) {
        float v = acc[m][n][r] * srow[m][r] * scol[n];
        acc[m][n][r] = v;
        mx = fmaxf(mx, v);
      }
      mx = fmaxf(mx, __shfl_xor(mx, 1));
      mx = fmaxf(mx, __shfl_xor(mx, 2));
      mx = fmaxf(mx, __shfl_xor(mx, 4));
      mx = fmaxf(mx, __shfl_xor(mx, 8));
      rmax[m][r] = mx;
    }
  if ((lane & 15) == 0) {
    #pragma unroll
    for (int m = 0; m < 4; ++m)
      #pragma unroll
      for (int r = 0; r < 4; ++r)
        red_max[(m * 16 + ((lane >> 4) << 2) + r) * 16 + wv] = rmax[m][r];
  }
  __syncthreads();
  if (tid < 64) {
    float mx = red_max[tid * 16];
    #pragma unroll
    for (int g = 1; g < 16; ++g) mx = fmaxf(mx, red_max[tid * 16 + g]);
    red_maxf[tid] = mx;
  }
  __syncthreads();

  float gmax[4][4];
  #pragma unroll
  for (int m = 0; m < 4; ++m)
    #pragma unroll
    for (int r = 0; r < 4; ++r)
      gmax[m][r] = red_maxf[m * 16 + ((lane >> 4) << 2) + r];

  // V prefetch (4 sets): latency hides under exp/P-write VALU (T14)
  s16x8 vfA[2], vfB[2], vfC[2], vfD[2];
  LOADSETV(vfA, 0)
  LOADSETV(vfB, 1)
  LOADSETV(vfC, 2)
  LOADSETV(vfD, 3)

  float rs[4][4];
  #pragma unroll
  for (int m = 0; m < 4; ++m)
    #pragma unroll
    for (int r = 0; r < 4; ++r) rs[m][r] = 0.f;
  #pragma unroll
  for (int m = 0; m < 4; ++m)
    #pragma unroll
    for (int n = 0; n < 2; ++n)
      #pragma unroll
      for (int r = 0; r < 4; ++r) {
        int row = m * 16 + ((lane >> 4) << 2) + r;
        int col = wv * 32 + n * 16 + (lane & 15);
        float pv = __expf(acc[m][n][r] - gmax[m][r]);
        rs[m][r] += pv;
        *(__hip_bfloat16*)(ldsP + row * 1024 + ((col * 2) ^ ((row & 7) << 4))) =
            __float2bfloat16(pv);
      }
  #pragma unroll
  for (int m = 0; m < 4; ++m)
    #pragma unroll
    for (int r = 0; r < 4; ++r) {
      float s = rs[m][r];
      s += __shfl_xor(s, 1);
      s += __shfl_xor(s, 2);
      s += __shfl_xor(s, 4);
      s += __shfl_xor(s, 8);
      if ((lane & 15) == 0)
        red_sum[(m * 16 + ((lane >> 4) << 2) + r) * 16 + wv] = s;
    }
  __syncthreads();  // P + red_sum visible
  if (tid < 64) {
    float s = 0.f;
    #pragma unroll
    for (int g = 0; g < 16; ++g) s += red_sum[tid * 16 + g];
    rsinv[tid] = 1.f / s;
  }

  // ---- phase 2: O = P V; P from LDS, V via depth-4 asm pipeline ----
  f32x4 acc2[4][2];
  #pragma unroll
  for (int m = 0; m < 4; ++m)
    #pragma unroll
    for (int n = 0; n < 2; ++n) acc2[m][n] = (f32x4){0.f, 0.f, 0.f, 0.f};

  #pragma unroll
  for (int g = 0; g < 3; ++g) {
    { s16x8 pf[4]; LOADP(pf, 4 * g + 0) WAITV(6) MFMA8(pf, vfA, acc2) } LOADSETV(vfA, 4 * g + 4)
    { s16x8 pf[4]; LOADP(pf, 4 * g + 1) WAITV(6) MFMA8(pf, vfB, acc2) } LOADSETV(vfB, 4 * g + 5)
    { s16x8 pf[4]; LOADP(pf, 4 * g + 2) WAITV(6) MFMA8(pf, vfC, acc2) } LOADSETV(vfC, 4 * g + 6)
    { s16x8 pf[4]; LOADP(pf, 4 * g + 3) WAITV(6) MFMA8(pf, vfD, acc2) } LOADSETV(vfD, 4 * g + 7)
  }
  { s16x8 pf[4]; LOADP(pf, 12) WAITV(6) MFMA8(pf, vfA, acc2) }
  { s16x8 pf[4]; LOADP(pf, 13) WAITV(4) MFMA8(pf, vfB, acc2) }
  { s16x8 pf[4]; LOADP(pf, 14) WAITV(2) MFMA8(pf, vfC, acc2) }
  { s16x8 pf[4]; LOADP(pf, 15) WAITV(0) MFMA8(pf, vfD, acc2) }
  __syncthreads();  // P dead; reuse region for O staging

  float rinv[4][4];
  #pragma unroll
  for (int m = 0; m < 4; ++m)
    #pragma unroll
    for (int r = 0; r < 4; ++r)
      rinv[m][r] = rsinv[m * 16 + ((lane >> 4) << 2) + r];

  // stage O: each wave writes its 64-row x 64B col-slice into [64][1024B]
  #pragma unroll
  for (int m = 0; m < 4; ++m)
    #pragma unroll
    for (int n = 0; n < 2; ++n)
      #pragma unroll
      for (int r = 0; r < 4; ++r) {
        int row = m * 16 + ((lane >> 4) << 2) + r;
        int col = wv * 32 + n * 16 + (lane & 15);
        *(__hip_bfloat16*)(ldsP + row * 1024 + col * 2) =
            __float2bfloat16(acc2[m][n][r] * rinv[m][r]);
      }
  __syncthreads();
  {
    const int row = tid >> 4;
    const int seg = tid & 15;
    const char* src = ldsP + row * 1024 + seg * 64;
    char* dst = (char*)(Obuf + sbase + (size_t)w0 * HW) + (size_t)row * 1024 + seg * 64;
    #pragma unroll
    for (int i = 0; i < 4; ++i)
      *(s16x8*)(dst + i * 16) = *(const s16x8*)(src + i * 16);
  }
}

// ---------------------------------------------------------------------------
// Kernel 3: out[b][j][h][w] = sum_o wout[j][o] * O[b][o][w][h]  (unchanged)
// ---------------------------------------------------------------------------
__global__ __launch_bounds__(256) void proj_kernel(
    const __hip_bfloat16* __restrict__ Obuf, const float* __restrict__ wout,
    float* __restrict__ out)
{
  const int b = blockIdx.y;
  const int t = blockIdx.x;
  const int h0 = (t >> 5) * 64;
  const int w0 = (t & 31) * 16;
  const int tid = threadIdx.x;
  __shared__ float os[8][16][65];
  __shared__ float wo_s[64];
  if (tid < 64) wo_s[tid] = wout[tid];
  {
    int r = tid >> 4;
    int c4 = (tid & 15) * 4;
    #pragma unroll
    for (int o = 0; o < 8; ++o) {
      const __hip_bfloat16* p = Obuf + ((size_t)(b * 8 + o) * HW + w0 + r) * HW + h0 + c4;
      u16x4 v = *(const u16x4*)p;
      #pragma unroll
      for (int i = 0; i < 4; ++i)
        os[o][r][c4 + i] = __uint_as_float((unsigned)v[i] << 16);
    }
  }
  __syncthreads();
  const int w = tid & 15;
  #pragma unroll
  for (int ih = 0; ih < 4; ++ih) {
    int h = ih * 16 + (tid >> 4);
    float ov[8];
    #pragma unroll
    for (int o = 0; o < 8; ++o) ov[o] = os[o][w][h];
    #pragma unroll
    for (int jo = 0; jo < 8; ++jo) {
      float a = 0.f;
      #pragma unroll
      for (int o = 0; o < 8; ++o) a += ov[o] * wo_s[jo * 8 + o];
      out[((size_t)(b * 8 + jo) * HW + h0 + h) * HW + w0 + w] = a;
    }
  }
}

extern "C" void kernel_launch(void* const* d_in, const int* in_sizes, int n_in,
                              void* d_out, int out_size, void* d_ws, size_t ws_size,
                              hipStream_t stream) {
  (void)in_sizes; (void)n_in; (void)out_size; (void)ws_size;
  const float* x    = (const float*)d_in[0];
  const float* wqkv = (const float*)d_in[1];
  const float* wdw  = (const float*)d_in[2];
  const float* wout = (const float*)d_in[3];
  const float* temp = (const float*)d_in[4];
  float* out = (float*)d_out;

  char* ws = (char*)d_ws;
  const size_t plane = (size_t)NSLICE * HW * HW * 2;  // 64 MiB bf16 plane
  __hip_bfloat16* qT = (__hip_bfloat16*)(ws);
  __hip_bfloat16* kT = (__hip_bfloat16*)(ws + plane);
  __hip_bfloat16* vS = (__hip_bfloat16*)(ws + 2 * plane);
  __hip_bfloat16* Ob = (__hip_bfloat16*)(ws + 3 * plane);
  float* qss = (float*)(ws + 4 * plane);
  float* kss = (float*)(ws + 4 * plane + (size_t)NSLICE * HW * 4);

  hipMemsetAsync(qss, 0, 2 * (size_t)NSLICE * HW * 4, stream);
  qkv_fused<<<dim3(256, 16), 256, 0, stream>>>(x, wqkv, wdw, qT, kT, vS, qss, kss);
  hipFuncSetAttribute((const void*)attn_kernel,
                      hipFuncAttributeMaxDynamicSharedMemorySize, ATTN_LDS_SIZE);
  attn_kernel<<<dim3(1024), 1024, ATTN_LDS_SIZE, stream>>>(qT, kT, vS, Ob, qss, kss, temp);
  proj_kernel<<<dim3(256, 16), 256, 0, stream>>>(Ob, wout, out);
}

// Round 18
// 315.165 us; speedup vs baseline: 1.8039x; 1.0405x over previous
//
#include <hip/hip_runtime.h>
#include <hip/hip_bf16.h>

typedef __attribute__((ext_vector_type(4))) float f32x4;
typedef __attribute__((ext_vector_type(2))) float f32x2;
typedef __attribute__((ext_vector_type(8))) short s16x8;
typedef __attribute__((ext_vector_type(4))) short s16x4;
typedef __attribute__((ext_vector_type(4))) unsigned short u16x4;

#define HW 512
#define NSLICE 128  // 16 b * 8 ch

union B4 { s16x4 v; __hip_bfloat16 e[4]; };

// ---------------------------------------------------------------------------
// Kernel 1: fused conv1x1 + dw3x3 — R13 VERBATIM (measured best).
// ---------------------------------------------------------------------------
__global__ __launch_bounds__(256) void qkv_fused(
    const float* __restrict__ x, const float* __restrict__ wqkv,
    const float* __restrict__ wdw,
    __hip_bfloat16* __restrict__ qT, __hip_bfloat16* __restrict__ kT,
    __hip_bfloat16* __restrict__ vS,
    float* __restrict__ qss, float* __restrict__ kss)
{
  const int b = blockIdx.y;
  const int tile = blockIdx.x;
  const int h0 = (tile >> 4) * 32;
  const int w0 = (tile & 15) * 32;
  const int tid = threadIdx.x;

  __shared__ float ts[4][1156][2];
  __shared__ float colsq[4][8][32];
  __shared__ float wq_s[24][8];
  __shared__ float wd_s[24][12];

  if (tid < 192) wq_s[tid >> 3][tid & 7] = wqkv[tid];
  if (tid < 216) wd_s[tid / 9][tid % 9] = wdw[tid];

  float xr[5][8];
  #pragma unroll
  for (int p = 0; p < 5; ++p) {
    int i = tid + p * 256;
    if (i < 1156) {
      int ih = h0 - 1 + i / 34, iw = w0 - 1 + i % 34;
      bool ok = (ih >= 0 && ih < HW && iw >= 0 && iw < HW);
      #pragma unroll
      for (int c = 0; c < 8; ++c)
        xr[p][c] = ok ? x[((size_t)(b * 8 + c) * HW + ih) * HW + iw] : 0.f;
    }
  }
  __syncthreads();

  const int tw = tid & 31;
  const int th = tid >> 5;
  const int lane = tid & 63;
  const int wv = tid >> 6;

  #pragma unroll
  for (int g = 0; g < 3; ++g) {
    #pragma unroll
    for (int p = 0; p < 5; ++p) {
      int i = tid + p * 256;
      if (i < 1156) {
        #pragma unroll
        for (int op = 0; op < 4; ++op) {
          const int o = g * 8 + op * 2;
          float a0 = 0.f, a1 = 0.f;
          #pragma unroll
          for (int c = 0; c < 8; ++c) {
            a0 += xr[p][c] * wq_s[o][c];
            a1 += xr[p][c] * wq_s[o + 1][c];
          }
          ts[op][i][0] = a0;
          ts[op][i][1] = a1;
        }
      }
    }
    __syncthreads();

    #pragma unroll
    for (int op = 0; op < 4; ++op) {
      const int o = g * 8 + op * 2;
      float w2[6][3][2];
      #pragma unroll
      for (int r = 0; r < 6; ++r)
        #pragma unroll
        for (int c = 0; c < 3; ++c) {
          f32x2 v = *(const f32x2*)&ts[op][(4 * th + r) * 34 + tw + c][0];
          w2[r][c][0] = v[0];
          w2[r][c][1] = v[1];
        }
      float o0[4], o1[4];
      #pragma unroll
      for (int r = 0; r < 4; ++r) { o0[r] = 0.f; o1[r] = 0.f; }
      #pragma unroll
      for (int di = 0; di < 3; ++di)
        #pragma unroll
        for (int dj = 0; dj < 3; ++dj) {
          const float wd0 = wd_s[o][di * 3 + dj];
          const float wd1 = wd_s[o + 1][di * 3 + dj];
          #pragma unroll
          for (int r = 0; r < 4; ++r) {
            o0[r] += w2[r + di][dj][0] * wd0;
            o1[r] += w2[r + di][dj][1] * wd1;
          }
        }
      if (g < 2) {
        float s0 = o0[0]*o0[0] + o0[1]*o0[1] + o0[2]*o0[2] + o0[3]*o0[3];
        float s1 = o1[0]*o1[0] + o1[1]*o1[1] + o1[2]*o1[2] + o1[3]*o1[3];
        s0 += __shfl_xor(s0, 32);
        s1 += __shfl_xor(s1, 32);
        if (lane < 32) {
          colsq[wv][op * 2][tw] = s0;
          colsq[wv][op * 2 + 1][tw] = s1;
        }
        B4 u0, u1;
        #pragma unroll
        for (int r = 0; r < 4; ++r) {
          u0.e[r] = __float2bfloat16(o0[r]);
          u1.e[r] = __float2bfloat16(o1[r]);
        }
        __hip_bfloat16* base = (g == 0) ? qT : kT;
        size_t a0i = (size_t)(b * 8 + op * 2) * HW * HW
                   + (size_t)(h0 >> 5) * HW * 32 + (size_t)(w0 + tw) * 32 + 4 * th;
        *(s16x4*)(base + a0i) = u0.v;
        *(s16x4*)(base + a0i + (size_t)HW * HW) = u1.v;
      } else {
        __hip_bfloat16* vb0 = vS + (size_t)(b * 8 + op * 2) * HW * HW
                            + (size_t)(w0 >> 5) * HW * 32 + (size_t)(h0 + 4 * th) * 32 + tw;
        __hip_bfloat16* vb1 = vb0 + (size_t)HW * HW;
        #pragma unroll
        for (int r = 0; r < 4; ++r) {
          vb0[r * 32] = __float2bfloat16(o0[r]);
          vb1[r * 32] = __float2bfloat16(o1[r]);
        }
      }
    }
    __syncthreads();

    if (g < 2) {
      const int o = tid >> 5, w = tid & 31;
      float s = colsq[0][o][w] + colsq[1][o][w] + colsq[2][o][w] + colsq[3][o][w];
      float* dst = (g == 0 ? qss : kss) + (size_t)(b * 8 + o) * HW + w0 + w;
      atomicAdd(dst, s);
    }
  }
}

// ---------------------------------------------------------------------------
// Kernel 2: per-slice attention — R13 frame (512 thr, 8 waves, BM=64,
// (512,1) => 256-reg budget, no spill) with K/V pipeline deepened to
// 8 GL4 sets (32 loads outstanding, 8-step lookahead). Steady WAITV(28),
// drain 28->0. Peak live ~220 < 256. WRITE_SIZE = spill tripwire.
// ---------------------------------------------------------------------------
#define QROW 1040
#define LDS_QP   0
#define OFF_RMAX 66560
#define OFF_RSUM 68608
#define OFF_RMAXF 70656
#define OFF_RSINV 70912
#define OFF_SQ   71168
#define OFF_SK   71424
#define ATTN_LDS_SIZE 73472

#define GL4(D, VOFF, BASE) \
  asm volatile("global_load_dwordx4 %0, %1, %2 offset:0"    : "=v"(D[0]) : "v"(VOFF), "s"(BASE)); \
  asm volatile("global_load_dwordx4 %0, %1, %2 offset:1024" : "=v"(D[1]) : "v"(VOFF), "s"(BASE)); \
  asm volatile("global_load_dwordx4 %0, %1, %2 offset:2048" : "=v"(D[2]) : "v"(VOFF), "s"(BASE)); \
  asm volatile("global_load_dwordx4 %0, %1, %2 offset:3072" : "=v"(D[3]) : "v"(VOFF), "s"(BASE));

#define LOADSETK(BF, CHN) { \
  const char* bk_ = ks + (size_t)(CHN) * 32768; \
  GL4(BF, voffK, bk_) }

#define LOADSETV(VF, CHN) { \
  const char* bv_ = vs + (size_t)(CHN) * 32768; \
  GL4(VF, voffK, bv_) }

#define WAITV(N) \
  asm volatile("s_waitcnt vmcnt(" #N ")"); \
  __builtin_amdgcn_sched_barrier(0);

#define LDSQ(QF, S) { \
    const int cq_ = (S) * 64 + klo; \
    _Pragma("unroll") for (int m_ = 0; m_ < 4; ++m_) \
      QF[m_] = *(const s16x8*)(ldsQ + (m_ * 16 + arow) * QROW + cq_); }

#define LOADP(AF, S) { \
    const int cbp_ = (S) * 64 + klo; \
    _Pragma("unroll") for (int m_ = 0; m_ < 4; ++m_) { \
      const int row_ = m_ * 16 + arow; \
      AF[m_] = *(const s16x8*)(ldsP + row_ * 1024 + (cbp_ ^ ((row_ & 7) << 4))); } }
#define MFMA16(AF, BF, ACC) { \
    _Pragma("unroll") for (int m_ = 0; m_ < 4; ++m_) \
      _Pragma("unroll") for (int n_ = 0; n_ < 4; ++n_) \
        ACC[m_][n_] = __builtin_amdgcn_mfma_f32_16x16x32_bf16(AF[m_], BF[n_], ACC[m_][n_], 0, 0, 0); }

__global__ __launch_bounds__(512, 1) void attn_kernel(
    const __hip_bfloat16* __restrict__ qT, const __hip_bfloat16* __restrict__ kT,
    const __hip_bfloat16* __restrict__ vS, __hip_bfloat16* __restrict__ Obuf,
    const float* __restrict__ qss, const float* __restrict__ kss,
    const float* __restrict__ temp)
{
  extern __shared__ char smem[];
  char* ldsQ = smem + LDS_QP;
  char* ldsP = smem + LDS_QP;
  float* red_max  = (float*)(smem + OFF_RMAX);
  float* red_sum  = (float*)(smem + OFF_RSUM);
  float* red_maxf = (float*)(smem + OFF_RMAXF);
  float* rsinv    = (float*)(smem + OFF_RSINV);
  float* sq_l     = (float*)(smem + OFF_SQ);
  float* sk_l     = (float*)(smem + OFF_SK);

  const int tid = threadIdx.x;
  const int lane = tid & 63;
  const int wv = tid >> 6;
  const int p = blockIdx.x;
  const int slice = (p & 7) + 8 * (p >> 6);
  const int rblk = (p >> 3) & 7;
  const int w0 = rblk * 64;
  const size_t sbase = (size_t)slice * HW * HW;
  const char* qs = (const char*)(qT + sbase);
  const char* ks = (const char*)(kT + sbase);
  const char* vs = (const char*)(vS + sbase);

  const int klo = (lane >> 4) << 4;
  const int arow = lane & 15;
  const int voffK = (wv * 64 + arow) * 64 + klo;

  {
    const int r = tid >> 3;
    const int seg = tid & 7;
    #pragma unroll
    for (int i = 0; i < 8; ++i) {
      const int chn_i = seg * 2 + (i >> 2);
      s16x8 v = *(const s16x8*)(qs + (size_t)chn_i * 32768 + (size_t)(w0 + r) * 64 + (i & 3) * 16);
      *(s16x8*)(ldsQ + r * QROW + seg * 128 + i * 16) = v;
    }
  }
  const float tmp = temp[(slice & 7) >> 1];
  if (tid < 64) sq_l[tid] = tmp / fmaxf(sqrtf(qss[(size_t)slice * HW + w0 + tid]), 1e-12f);
  sk_l[tid] = 1.f / fmaxf(sqrtf(kss[(size_t)slice * HW + tid]), 1e-12f);
  __syncthreads();

  f32x4 acc[4][4];
  #pragma unroll
  for (int m = 0; m < 4; ++m)
    #pragma unroll
    for (int n = 0; n < 4; ++n) acc[m][n] = (f32x4){0.f, 0.f, 0.f, 0.f};
  __builtin_amdgcn_sched_barrier(0);

  // ---- phase 1: S = Q K^T; Q from LDS, K via depth-8 GL4 pipeline ----
  s16x8 bfA[4], bfB[4], bfC[4], bfD[4], bfE[4], bfF[4], bfG[4], bfH[4];
  LOADSETK(bfA, 0) LOADSETK(bfB, 1) LOADSETK(bfC, 2) LOADSETK(bfD, 3)
  LOADSETK(bfE, 4) LOADSETK(bfF, 5) LOADSETK(bfG, 6) LOADSETK(bfH, 7)

  { s16x8 qf[4]; LDSQ(qf, 0)  WAITV(28) MFMA16(qf, bfA, acc) } LOADSETK(bfA, 8)
  { s16x8 qf[4]; LDSQ(qf, 1)  WAITV(28) MFMA16(qf, bfB, acc) } LOADSETK(bfB, 9)
  { s16x8 qf[4]; LDSQ(qf, 2)  WAITV(28) MFMA16(qf, bfC, acc) } LOADSETK(bfC, 10)
  { s16x8 qf[4]; LDSQ(qf, 3)  WAITV(28) MFMA16(qf, bfD, acc) } LOADSETK(bfD, 11)
  { s16x8 qf[4]; LDSQ(qf, 4)  WAITV(28) MFMA16(qf, bfE, acc) } LOADSETK(bfE, 12)
  { s16x8 qf[4]; LDSQ(qf, 5)  WAITV(28) MFMA16(qf, bfF, acc) } LOADSETK(bfF, 13)
  { s16x8 qf[4]; LDSQ(qf, 6)  WAITV(28) MFMA16(qf, bfG, acc) } LOADSETK(bfG, 14)
  { s16x8 qf[4]; LDSQ(qf, 7)  WAITV(28) MFMA16(qf, bfH, acc) } LOADSETK(bfH, 15)
  { s16x8 qf[4]; LDSQ(qf, 8)  WAITV(28) MFMA16(qf, bfA, acc) }
  { s16x8 qf[4]; LDSQ(qf, 9)  WAITV(24) MFMA16(qf, bfB, acc) }
  { s16x8 qf[4]; LDSQ(qf, 10) WAITV(20) MFMA16(qf, bfC, acc) }
  { s16x8 qf[4]; LDSQ(qf, 11) WAITV(16) MFMA16(qf, bfD, acc) }
  { s16x8 qf[4]; LDSQ(qf, 12) WAITV(12) MFMA16(qf, bfE, acc) }
  { s16x8 qf[4]; LDSQ(qf, 13) WAITV(8)  MFMA16(qf, bfF, acc) }
  { s16x8 qf[4]; LDSQ(qf, 14) WAITV(4)  MFMA16(qf, bfG, acc) }
  { s16x8 qf[4]; LDSQ(qf, 15) WAITV(0)  MFMA16(qf, bfH, acc) }
  __syncthreads();  // Q dead; P may overwrite

  // ---- softmax over v (rows w) ----
  float srow[4][4], scol[4];
  #pragma unroll
  for (int m = 0; m < 4; ++m)
    #pragma unroll
    for (int r = 0; r < 4; ++r)
      srow[m][r] = sq_l[m * 16 + ((lane >> 4) << 2) + r];
  #pragma unroll
  for (int n = 0; n < 4; ++n) scol[n] = sk_l[wv * 64 + n * 16 + (lane & 15)];

  float rmax[4][4];
  #pragma unroll
  for (int m = 0; m < 4; ++m)
    #pragma unroll
    for (int r = 0; r < 4; ++r) {
      float mx = -1e30f;
      #pragma unroll
      for (int n = 0; n < 4; ++n) {
        float v = acc[m][n][r] * srow[m][r] * scol[n];
        acc[m][n][r] = v;
        mx = fmaxf(mx, v);
      }
      mx = fmaxf(mx, __shfl_xor(mx, 1));
      mx = fmaxf(mx, __shfl_xor(mx, 2));
      mx = fmaxf(mx, __shfl_xor(mx, 4));
      mx = fmaxf(mx, __shfl_xor(mx, 8));
      rmax[m][r] = mx;
    }
  if ((lane & 15) == 0) {
    #pragma unroll
    for (int m = 0; m < 4; ++m)
      #pragma unroll
      for (int r = 0; r < 4; ++r)
        red_max[(m * 16 + ((lane >> 4) << 2) + r) * 8 + wv] = rmax[m][r];
  }
  __syncthreads();
  if (tid < 64) {
    float mx = red_max[tid * 8];
    #pragma unroll
    for (int g = 1; g < 8; ++g) mx = fmaxf(mx, red_max[tid * 8 + g]);
    red_maxf[tid] = mx;
  }
  __syncthreads();

  float gmax[4][4];
  #pragma unroll
  for (int m = 0; m < 4; ++m)
    #pragma unroll
    for (int r = 0; r < 4; ++r)
      gmax[m][r] = red_maxf[m * 16 + ((lane >> 4) << 2) + r];

  // V prefetch: 4 sets now (not 8 — keeps softmax-section live set bounded);
  // remaining sets stream in phase 2 with 8-deep steady state.
  s16x8 vfA[4], vfB[4], vfC[4], vfD[4], vfE[4], vfF[4], vfG[4], vfH[4];
  LOADSETV(vfA, 0) LOADSETV(vfB, 1) LOADSETV(vfC, 2) LOADSETV(vfD, 3)

  float rs[4][4];
  #pragma unroll
  for (int m = 0; m < 4; ++m)
    #pragma unroll
    for (int r = 0; r < 4; ++r) rs[m][r] = 0.f;
  #pragma unroll
  for (int m = 0; m < 4; ++m)
    #pragma unroll
    for (int n = 0; n < 4; ++n)
      #pragma unroll
      for (int r = 0; r < 4; ++r) {
        int row = m * 16 + ((lane >> 4) << 2) + r;
        int col = wv * 64 + n * 16 + (lane & 15);
        float pv = __expf(acc[m][n][r] - gmax[m][r]);
        rs[m][r] += pv;
        *(__hip_bfloat16*)(ldsP + row * 1024 + ((col * 2) ^ ((row & 7) << 4))) =
            __float2bfloat16(pv);
      }
  #pragma unroll
  for (int m = 0; m < 4; ++m)
    #pragma unroll
    for (int r = 0; r < 4; ++r) {
      float s = rs[m][r];
      s += __shfl_xor(s, 1);
      s += __shfl_xor(s, 2);
      s += __shfl_xor(s, 4);
      s += __shfl_xor(s, 8);
      if ((lane & 15) == 0)
        red_sum[(m * 16 + ((lane >> 4) << 2) + r) * 8 + wv] = s;
    }
  __syncthreads();  // P + red_sum visible (drains V prefetch: values landed)
  if (tid < 64) {
    float s = 0.f;
    #pragma unroll
    for (int g = 0; g < 8; ++g) s += red_sum[tid * 8 + g];
    rsinv[tid] = 1.f / s;
  }

  // ---- phase 2: O = P V; build up to 8 sets in flight ----
  f32x4 acc2[4][4];
  #pragma unroll
  for (int m = 0; m < 4; ++m)
    #pragma unroll
    for (int n = 0; n < 4; ++n) acc2[m][n] = (f32x4){0.f, 0.f, 0.f, 0.f};

  // issue 4 more sets: 8 in flight total (barrier drained the first 4, but
  // their values are already in registers — safe)
  LOADSETV(vfE, 4) LOADSETV(vfF, 5) LOADSETV(vfG, 6) LOADSETV(vfH, 7)

  { s16x8 pf[4]; LOADP(pf, 0)  WAITV(12) MFMA16(pf, vfA, acc2) } LOADSETV(vfA, 8)
  { s16x8 pf[4]; LOADP(pf, 1)  WAITV(12) MFMA16(pf, vfB, acc2) } LOADSETV(vfB, 9)
  { s16x8 pf[4]; LOADP(pf, 2)  WAITV(12) MFMA16(pf, vfC, acc2) } LOADSETV(vfC, 10)
  { s16x8 pf[4]; LOADP(pf, 3)  WAITV(12) MFMA16(pf, vfD, acc2) } LOADSETV(vfD, 11)
  { s16x8 pf[4]; LOADP(pf, 4)  WAITV(28) MFMA16(pf, vfE, acc2) } LOADSETV(vfE, 12)
  { s16x8 pf[4]; LOADP(pf, 5)  WAITV(28) MFMA16(pf, vfF, acc2) } LOADSETV(vfF, 13)
  { s16x8 pf[4]; LOADP(pf, 6)  WAITV(28) MFMA16(pf, vfG, acc2) } LOADSETV(vfG, 14)
  { s16x8 pf[4]; LOADP(pf, 7)  WAITV(28) MFMA16(pf, vfH, acc2) } LOADSETV(vfH, 15)
  { s16x8 pf[4]; LOADP(pf, 8)  WAITV(28) MFMA16(pf, vfA, acc2) }
  { s16x8 pf[4]; LOADP(pf, 9)  WAITV(24) MFMA16(pf, vfB, acc2) }
  { s16x8 pf[4]; LOADP(pf, 10) WAITV(20) MFMA16(pf, vfC, acc2) }
  { s16x8 pf[4]; LOADP(pf, 11) WAITV(16) MFMA16(pf, vfD, acc2) }
  { s16x8 pf[4]; LOADP(pf, 12) WAITV(12) MFMA16(pf, vfE, acc2) }
  { s16x8 pf[4]; LOADP(pf, 13) WAITV(8)  MFMA16(pf, vfF, acc2) }
  { s16x8 pf[4]; LOADP(pf, 14) WAITV(4)  MFMA16(pf, vfG, acc2) }
  { s16x8 pf[4]; LOADP(pf, 15) WAITV(0)  MFMA16(pf, vfH, acc2) }
  __syncthreads();  // P dead; reuse LDS for O staging

  float rinv[4][4];
  #pragma unroll
  for (int m = 0; m < 4; ++m)
    #pragma unroll
    for (int r = 0; r < 4; ++r)
      rinv[m][r] = rsinv[m * 16 + ((lane >> 4) << 2) + r];

  char* ldsO = ldsP + wv * 8192;
  #pragma unroll
  for (int m = 0; m < 4; ++m)
    #pragma unroll
    for (int n = 0; n < 4; ++n)
      #pragma unroll
      for (int r = 0; r < 4; ++r) {
        int row = m * 16 + ((lane >> 4) << 2) + r;
        int col = n * 16 + (lane & 15);
        *(__hip_bfloat16*)(ldsO + row * 128 + col * 2) =
            __float2bfloat16(acc2[m][n][r] * rinv[m][r]);
      }
  __syncthreads();
  __hip_bfloat16* ob = Obuf + sbase + (size_t)w0 * HW + wv * 64;
  #pragma unroll
  for (int it = 0; it < 8; ++it) {
    int row = it * 8 + (lane >> 3);
    int c = (lane & 7) << 4;
    s16x8 v = *(const s16x8*)(ldsO + row * 128 + c);
    *(s16x8*)((char*)ob + (size_t)row * 1024 + c) = v;
  }
}

// ---------------------------------------------------------------------------
// Kernel 3: proj (unchanged)
// ---------------------------------------------------------------------------
__global__ __launch_bounds__(256) void proj_kernel(
    const __hip_bfloat16* __restrict__ Obuf, const float* __restrict__ wout,
    float* __restrict__ out)
{
  const int b = blockIdx.y;
  const int t = blockIdx.x;
  const int h0 = (t >> 5) * 64;
  const int w0 = (t & 31) * 16;
  const int tid = threadIdx.x;
  __shared__ float os[8][16][65];
  __shared__ float wo_s[64];
  if (tid < 64) wo_s[tid] = wout[tid];
  {
    int r = tid >> 4;
    int c4 = (tid & 15) * 4;
    #pragma unroll
    for (int o = 0; o < 8; ++o) {
      const __hip_bfloat16* p = Obuf + ((size_t)(b * 8 + o) * HW + w0 + r) * HW + h0 + c4;
      u16x4 v = *(const u16x4*)p;
      #pragma unroll
      for (int i = 0; i < 4; ++i)
        os[o][r][c4 + i] = __uint_as_float((unsigned)v[i] << 16);
    }
  }
  __syncthreads();
  const int w = tid & 15;
  #pragma unroll
  for (int ih = 0; ih < 4; ++ih) {
    int h = ih * 16 + (tid >> 4);
    float ov[8];
    #pragma unroll
    for (int o = 0; o < 8; ++o) ov[o] = os[o][w][h];
    #pragma unroll
    for (int jo = 0; jo < 8; ++jo) {
      float a = 0.f;
      #pragma unroll
      for (int o = 0; o < 8; ++o) a += ov[o] * wo_s[jo * 8 + o];
      out[((size_t)(b * 8 + jo) * HW + h0 + h) * HW + w0 + w] = a;
    }
  }
}

extern "C" void kernel_launch(void* const* d_in, const int* in_sizes, int n_in,
                              void* d_out, int out_size, void* d_ws, size_t ws_size,
                              hipStream_t stream) {
  (void)in_sizes; (void)n_in; (void)out_size; (void)ws_size;
  const float* x    = (const float*)d_in[0];
  const float* wqkv = (const float*)d_in[1];
  const float* wdw  = (const float*)d_in[2];
  const float* wout = (const float*)d_in[3];
  const float* temp = (const float*)d_in[4];
  float* out = (float*)d_out;

  char* ws = (char*)d_ws;
  const size_t plane = (size_t)NSLICE * HW * HW * 2;  // 64 MiB bf16 plane
  __hip_bfloat16* qT = (__hip_bfloat16*)(ws);
  __hip_bfloat16* kT = (__hip_bfloat16*)(ws + plane);
  __hip_bfloat16* vS = (__hip_bfloat16*)(ws + 2 * plane);
  __hip_bfloat16* Ob = (__hip_bfloat16*)(ws + 3 * plane);
  float* qss = (float*)(ws + 4 * plane);
  float* kss = (float*)(ws + 4 * plane + (size_t)NSLICE * HW * 4);

  hipMemsetAsync(qss, 0, 2 * (size_t)NSLICE * HW * 4, stream);
  qkv_fused<<<dim3(256, 16), 256, 0, stream>>>(x, wqkv, wdw, qT, kT, vS, qss, kss);
  hipFuncSetAttribute((const void*)attn_kernel,
                      hipFuncAttributeMaxDynamicSharedMemorySize, ATTN_LDS_SIZE);
  attn_kernel<<<dim3(1024), 512, ATTN_LDS_SIZE, stream>>>(qT, kT, vS, Ob, qss, kss, temp);
  proj_kernel<<<dim3(256, 16), 256, 0, stream>>>(Ob, wout, out);
}

// Round 19
// 312.100 us; speedup vs baseline: 1.8216x; 1.0098x over previous
//
#include <hip/hip_runtime.h>
#include <hip/hip_bf16.h>

typedef __attribute__((ext_vector_type(4))) float f32x4;
typedef __attribute__((ext_vector_type(2))) float f32x2;
typedef __attribute__((ext_vector_type(8))) short s16x8;
typedef __attribute__((ext_vector_type(4))) short s16x4;
typedef __attribute__((ext_vector_type(4))) unsigned short u16x4;

#define HW 512
#define NSLICE 128  // 16 b * 8 ch

union B4 { s16x4 v; __hip_bfloat16 e[4]; };

// ---------------------------------------------------------------------------
// FINAL CONFIGURATION (best measured: 312.9 us total, R13).
// Kernel 1: fused conv1x1 (8->24ch) + depthwise 3x3 + head-split.
// ts-staged conv intermediate, direct register->global stores (no ot buffer),
// 42.9 KB LDS -> 3 blocks/CU. Chunked output layout [slice][chn][row][32
// bf16]: qT/kT chn=h/32,row=w ; vS chn=v/32,row=h — makes every attention
// fragment load one contiguous 1KB wave-transaction.
// ---------------------------------------------------------------------------
__global__ __launch_bounds__(256) void qkv_fused(
    const float* __restrict__ x, const float* __restrict__ wqkv,
    const float* __restrict__ wdw,
    __hip_bfloat16* __restrict__ qT, __hip_bfloat16* __restrict__ kT,
    __hip_bfloat16* __restrict__ vS,
    float* __restrict__ qss, float* __restrict__ kss)
{
  const int b = blockIdx.y;
  const int tile = blockIdx.x;
  const int h0 = (tile >> 4) * 32;
  const int w0 = (tile & 15) * 32;
  const int tid = threadIdx.x;

  __shared__ float ts[4][1156][2];
  __shared__ float colsq[4][8][32];
  __shared__ float wq_s[24][8];
  __shared__ float wd_s[24][12];

  if (tid < 192) wq_s[tid >> 3][tid & 7] = wqkv[tid];
  if (tid < 216) wd_s[tid / 9][tid % 9] = wdw[tid];

  float xr[5][8];
  #pragma unroll
  for (int p = 0; p < 5; ++p) {
    int i = tid + p * 256;
    if (i < 1156) {
      int ih = h0 - 1 + i / 34, iw = w0 - 1 + i % 34;
      bool ok = (ih >= 0 && ih < HW && iw >= 0 && iw < HW);
      #pragma unroll
      for (int c = 0; c < 8; ++c)
        xr[p][c] = ok ? x[((size_t)(b * 8 + c) * HW + ih) * HW + iw] : 0.f;
    }
  }
  __syncthreads();

  const int tw = tid & 31;
  const int th = tid >> 5;
  const int lane = tid & 63;
  const int wv = tid >> 6;

  #pragma unroll
  for (int g = 0; g < 3; ++g) {
    #pragma unroll
    for (int p = 0; p < 5; ++p) {
      int i = tid + p * 256;
      if (i < 1156) {
        #pragma unroll
        for (int op = 0; op < 4; ++op) {
          const int o = g * 8 + op * 2;
          float a0 = 0.f, a1 = 0.f;
          #pragma unroll
          for (int c = 0; c < 8; ++c) {
            a0 += xr[p][c] * wq_s[o][c];
            a1 += xr[p][c] * wq_s[o + 1][c];
          }
          ts[op][i][0] = a0;
          ts[op][i][1] = a1;
        }
      }
    }
    __syncthreads();

    #pragma unroll
    for (int op = 0; op < 4; ++op) {
      const int o = g * 8 + op * 2;
      float w2[6][3][2];
      #pragma unroll
      for (int r = 0; r < 6; ++r)
        #pragma unroll
        for (int c = 0; c < 3; ++c) {
          f32x2 v = *(const f32x2*)&ts[op][(4 * th + r) * 34 + tw + c][0];
          w2[r][c][0] = v[0];
          w2[r][c][1] = v[1];
        }
      float o0[4], o1[4];
      #pragma unroll
      for (int r = 0; r < 4; ++r) { o0[r] = 0.f; o1[r] = 0.f; }
      #pragma unroll
      for (int di = 0; di < 3; ++di)
        #pragma unroll
        for (int dj = 0; dj < 3; ++dj) {
          const float wd0 = wd_s[o][di * 3 + dj];
          const float wd1 = wd_s[o + 1][di * 3 + dj];
          #pragma unroll
          for (int r = 0; r < 4; ++r) {
            o0[r] += w2[r + di][dj][0] * wd0;
            o1[r] += w2[r + di][dj][1] * wd1;
          }
        }
      if (g < 2) {
        float s0 = o0[0]*o0[0] + o0[1]*o0[1] + o0[2]*o0[2] + o0[3]*o0[3];
        float s1 = o1[0]*o1[0] + o1[1]*o1[1] + o1[2]*o1[2] + o1[3]*o1[3];
        s0 += __shfl_xor(s0, 32);
        s1 += __shfl_xor(s1, 32);
        if (lane < 32) {
          colsq[wv][op * 2][tw] = s0;
          colsq[wv][op * 2 + 1][tw] = s1;
        }
        B4 u0, u1;
        #pragma unroll
        for (int r = 0; r < 4; ++r) {
          u0.e[r] = __float2bfloat16(o0[r]);
          u1.e[r] = __float2bfloat16(o1[r]);
        }
        __hip_bfloat16* base = (g == 0) ? qT : kT;
        size_t a0i = (size_t)(b * 8 + op * 2) * HW * HW
                   + (size_t)(h0 >> 5) * HW * 32 + (size_t)(w0 + tw) * 32 + 4 * th;
        *(s16x4*)(base + a0i) = u0.v;
        *(s16x4*)(base + a0i + (size_t)HW * HW) = u1.v;
      } else {
        __hip_bfloat16* vb0 = vS + (size_t)(b * 8 + op * 2) * HW * HW
                            + (size_t)(w0 >> 5) * HW * 32 + (size_t)(h0 + 4 * th) * 32 + tw;
        __hip_bfloat16* vb1 = vb0 + (size_t)HW * HW;
        #pragma unroll
        for (int r = 0; r < 4; ++r) {
          vb0[r * 32] = __float2bfloat16(o0[r]);
          vb1[r * 32] = __float2bfloat16(o1[r]);
        }
      }
    }
    __syncthreads();

    if (g < 2) {
      const int o = tid >> 5, w = tid & 31;
      float s = colsq[0][o][w] + colsq[1][o][w] + colsq[2][o][w] + colsq[3][o][w];
      float* dst = (g == 0 ? qss : kss) + (size_t)(b * 8 + o) * HW + w0 + w;
      atomicAdd(dst, s);
    }
  }
}

// ---------------------------------------------------------------------------
// Kernel 2: per-slice attention (best measured config): 512 thr / 8 waves,
// BM=64, chunked layout, Q deduped via LDS (1040B padded rows), K/V via
// asm-pinned depth-4 GL4 pipeline with counted vmcnt (steady WAITV(12)),
// (512,1) — VGPR 92, zero spill, 1 block/CU.
// Plateau note: depth {2,4,8} x occupancy {2,4 w/SIMD} all measure ~153 us;
// no counter saturates — structurally bound by serialized phase mix.
// ---------------------------------------------------------------------------
#define QROW 1040
#define LDS_QP   0
#define OFF_RMAX 66560
#define OFF_RSUM 68608
#define OFF_RMAXF 70656
#define OFF_RSINV 70912
#define OFF_SQ   71168
#define OFF_SK   71424
#define ATTN_LDS_SIZE 73472

#define GL4(D, VOFF, BASE) \
  asm volatile("global_load_dwordx4 %0, %1, %2 offset:0"    : "=v"(D[0]) : "v"(VOFF), "s"(BASE)); \
  asm volatile("global_load_dwordx4 %0, %1, %2 offset:1024" : "=v"(D[1]) : "v"(VOFF), "s"(BASE)); \
  asm volatile("global_load_dwordx4 %0, %1, %2 offset:2048" : "=v"(D[2]) : "v"(VOFF), "s"(BASE)); \
  asm volatile("global_load_dwordx4 %0, %1, %2 offset:3072" : "=v"(D[3]) : "v"(VOFF), "s"(BASE));

#define LOADSETK(BF, CHN) { \
  const char* bk_ = ks + (size_t)(CHN) * 32768; \
  GL4(BF, voffK, bk_) }

#define LOADSETV(VF, CHN) { \
  const char* bv_ = vs + (size_t)(CHN) * 32768; \
  GL4(VF, voffK, bv_) }

#define WAITV(N) \
  asm volatile("s_waitcnt vmcnt(" #N ")"); \
  __builtin_amdgcn_sched_barrier(0);

#define LDSQ(QF, S) { \
    const int cq_ = (S) * 64 + klo; \
    _Pragma("unroll") for (int m_ = 0; m_ < 4; ++m_) \
      QF[m_] = *(const s16x8*)(ldsQ + (m_ * 16 + arow) * QROW + cq_); }

#define LOADP(AF, S) { \
    const int cbp_ = (S) * 64 + klo; \
    _Pragma("unroll") for (int m_ = 0; m_ < 4; ++m_) { \
      const int row_ = m_ * 16 + arow; \
      AF[m_] = *(const s16x8*)(ldsP + row_ * 1024 + (cbp_ ^ ((row_ & 7) << 4))); } }
#define MFMA16(AF, BF, ACC) { \
    _Pragma("unroll") for (int m_ = 0; m_ < 4; ++m_) \
      _Pragma("unroll") for (int n_ = 0; n_ < 4; ++n_) \
        ACC[m_][n_] = __builtin_amdgcn_mfma_f32_16x16x32_bf16(AF[m_], BF[n_], ACC[m_][n_], 0, 0, 0); }

__global__ __launch_bounds__(512, 1) void attn_kernel(
    const __hip_bfloat16* __restrict__ qT, const __hip_bfloat16* __restrict__ kT,
    const __hip_bfloat16* __restrict__ vS, __hip_bfloat16* __restrict__ Obuf,
    const float* __restrict__ qss, const float* __restrict__ kss,
    const float* __restrict__ temp)
{
  extern __shared__ char smem[];
  char* ldsQ = smem + LDS_QP;
  char* ldsP = smem + LDS_QP;
  float* red_max  = (float*)(smem + OFF_RMAX);
  float* red_sum  = (float*)(smem + OFF_RSUM);
  float* red_maxf = (float*)(smem + OFF_RMAXF);
  float* rsinv    = (float*)(smem + OFF_RSINV);
  float* sq_l     = (float*)(smem + OFF_SQ);
  float* sk_l     = (float*)(smem + OFF_SK);

  const int tid = threadIdx.x;
  const int lane = tid & 63;
  const int wv = tid >> 6;
  const int p = blockIdx.x;
  // XCD swizzle: 8 row-blocks of one slice share an XCD (K/V L2 reuse)
  const int slice = (p & 7) + 8 * (p >> 6);
  const int rblk = (p >> 3) & 7;
  const int w0 = rblk * 64;
  const size_t sbase = (size_t)slice * HW * HW;
  const char* qs = (const char*)(qT + sbase);
  const char* ks = (const char*)(kT + sbase);
  const char* vs = (const char*)(vS + sbase);

  const int klo = (lane >> 4) << 4;
  const int arow = lane & 15;
  const int voffK = (wv * 64 + arow) * 64 + klo;

  {
    const int r = tid >> 3;
    const int seg = tid & 7;
    #pragma unroll
    for (int i = 0; i < 8; ++i) {
      const int chn_i = seg * 2 + (i >> 2);
      s16x8 v = *(const s16x8*)(qs + (size_t)chn_i * 32768 + (size_t)(w0 + r) * 64 + (i & 3) * 16);
      *(s16x8*)(ldsQ + r * QROW + seg * 128 + i * 16) = v;
    }
  }
  const float tmp = temp[(slice & 7) >> 1];
  if (tid < 64) sq_l[tid] = tmp / fmaxf(sqrtf(qss[(size_t)slice * HW + w0 + tid]), 1e-12f);
  sk_l[tid] = 1.f / fmaxf(sqrtf(kss[(size_t)slice * HW + tid]), 1e-12f);
  __syncthreads();

  f32x4 acc[4][4];
  #pragma unroll
  for (int m = 0; m < 4; ++m)
    #pragma unroll
    for (int n = 0; n < 4; ++n) acc[m][n] = (f32x4){0.f, 0.f, 0.f, 0.f};
  __builtin_amdgcn_sched_barrier(0);

  s16x8 bfA[4], bfB[4], bfC[4], bfD[4];
  LOADSETK(bfA, 0)
  LOADSETK(bfB, 1)
  LOADSETK(bfC, 2)
  LOADSETK(bfD, 3)

  #pragma unroll
  for (int g = 0; g < 3; ++g) {
    { s16x8 qf[4]; LDSQ(qf, 4 * g + 0) WAITV(12) MFMA16(qf, bfA, acc) } LOADSETK(bfA, 4 * g + 4)
    { s16x8 qf[4]; LDSQ(qf, 4 * g + 1) WAITV(12) MFMA16(qf, bfB, acc) } LOADSETK(bfB, 4 * g + 5)
    { s16x8 qf[4]; LDSQ(qf, 4 * g + 2) WAITV(12) MFMA16(qf, bfC, acc) } LOADSETK(bfC, 4 * g + 6)
    { s16x8 qf[4]; LDSQ(qf, 4 * g + 3) WAITV(12) MFMA16(qf, bfD, acc) } LOADSETK(bfD, 4 * g + 7)
  }
  { s16x8 qf[4]; LDSQ(qf, 12) WAITV(12) MFMA16(qf, bfA, acc) }
  { s16x8 qf[4]; LDSQ(qf, 13) WAITV(8)  MFMA16(qf, bfB, acc) }
  { s16x8 qf[4]; LDSQ(qf, 14) WAITV(4)  MFMA16(qf, bfC, acc) }
  { s16x8 qf[4]; LDSQ(qf, 15) WAITV(0)  MFMA16(qf, bfD, acc) }
  __syncthreads();

  float srow[4][4], scol[4];
  #pragma unroll
  for (int m = 0; m < 4; ++m)
    #pragma unroll
    for (int r = 0; r < 4; ++r)
      srow[m][r] = sq_l[m * 16 + ((lane >> 4) << 2) + r];
  #pragma unroll
  for (int n = 0; n < 4; ++n) scol[n] = sk_l[wv * 64 + n * 16 + (lane & 15)];

  float rmax[4][4];
  #pragma unroll
  for (int m = 0; m < 4; ++m)
    #pragma unroll
    for (int r = 0; r < 4; ++r) {
      float mx = -1e30f;
      #pragma unroll
      for (int n = 0; n < 4; ++n) {
        float v = acc[m][n][r] * srow[m][r] * scol[n];
        acc[m][n][r] = v;
        mx = fmaxf(mx, v);
      }
      mx = fmaxf(mx, __shfl_xor(mx, 1));
      mx = fmaxf(mx, __shfl_xor(mx, 2));
      mx = fmaxf(mx, __shfl_xor(mx, 4));
      mx = fmaxf(mx, __shfl_xor(mx, 8));
      rmax[m][r] = mx;
    }
  if ((lane & 15) == 0) {
    #pragma unroll
    for (int m = 0; m < 4; ++m)
      #pragma unroll
      for (int r = 0; r < 4; ++r)
        red_max[(m * 16 + ((lane >> 4) << 2) + r) * 8 + wv] = rmax[m][r];
  }
  __syncthreads();
  if (tid < 64) {
    float mx = red_max[tid * 8];
    #pragma unroll
    for (int g = 1; g < 8; ++g) mx = fmaxf(mx, red_max[tid * 8 + g]);
    red_maxf[tid] = mx;
  }
  __syncthreads();

  float gmax[4][4];
  #pragma unroll
  for (int m = 0; m < 4; ++m)
    #pragma unroll
    for (int r = 0; r < 4; ++r)
      gmax[m][r] = red_maxf[m * 16 + ((lane >> 4) << 2) + r];

  s16x8 vfA[4], vfB[4], vfC[4], vfD[4];
  LOADSETV(vfA, 0)
  LOADSETV(vfB, 1)
  LOADSETV(vfC, 2)
  LOADSETV(vfD, 3)

  float rs[4][4];
  #pragma unroll
  for (int m = 0; m < 4; ++m)
    #pragma unroll
    for (int r = 0; r < 4; ++r) rs[m][r] = 0.f;
  #pragma unroll
  for (int m = 0; m < 4; ++m)
    #pragma unroll
    for (int n = 0; n < 4; ++n)
      #pragma unroll
      for (int r = 0; r < 4; ++r) {
        int row = m * 16 + ((lane >> 4) << 2) + r;
        int col = wv * 64 + n * 16 + (lane & 15);
        float pv = __expf(acc[m][n][r] - gmax[m][r]);
        rs[m][r] += pv;
        *(__hip_bfloat16*)(ldsP + row * 1024 + ((col * 2) ^ ((row & 7) << 4))) =
            __float2bfloat16(pv);
      }
  #pragma unroll
  for (int m = 0; m < 4; ++m)
    #pragma unroll
    for (int r = 0; r < 4; ++r) {
      float s = rs[m][r];
      s += __shfl_xor(s, 1);
      s += __shfl_xor(s, 2);
      s += __shfl_xor(s, 4);
      s += __shfl_xor(s, 8);
      if ((lane & 15) == 0)
        red_sum[(m * 16 + ((lane >> 4) << 2) + r) * 8 + wv] = s;
    }
  __syncthreads();
  if (tid < 64) {
    float s = 0.f;
    #pragma unroll
    for (int g = 0; g < 8; ++g) s += red_sum[tid * 8 + g];
    rsinv[tid] = 1.f / s;
  }

  f32x4 acc2[4][4];
  #pragma unroll
  for (int m = 0; m < 4; ++m)
    #pragma unroll
    for (int n = 0; n < 4; ++n) acc2[m][n] = (f32x4){0.f, 0.f, 0.f, 0.f};

  #pragma unroll
  for (int g = 0; g < 3; ++g) {
    { s16x8 pf[4]; LOADP(pf, 4 * g + 0) WAITV(12) MFMA16(pf, vfA, acc2) } LOADSETV(vfA, 4 * g + 4)
    { s16x8 pf[4]; LOADP(pf, 4 * g + 1) WAITV(12) MFMA16(pf, vfB, acc2) } LOADSETV(vfB, 4 * g + 5)
    { s16x8 pf[4]; LOADP(pf, 4 * g + 2) WAITV(12) MFMA16(pf, vfC, acc2) } LOADSETV(vfC, 4 * g + 6)
    { s16x8 pf[4]; LOADP(pf, 4 * g + 3) WAITV(12) MFMA16(pf, vfD, acc2) } LOADSETV(vfD, 4 * g + 7)
  }
  { s16x8 pf[4]; LOADP(pf, 12) WAITV(12) MFMA16(pf, vfA, acc2) }
  { s16x8 pf[4]; LOADP(pf, 13) WAITV(8)  MFMA16(pf, vfB, acc2) }
  { s16x8 pf[4]; LOADP(pf, 14) WAITV(4)  MFMA16(pf, vfC, acc2) }
  { s16x8 pf[4]; LOADP(pf, 15) WAITV(0)  MFMA16(pf, vfD, acc2) }
  __syncthreads();

  float rinv[4][4];
  #pragma unroll
  for (int m = 0; m < 4; ++m)
    #pragma unroll
    for (int r = 0; r < 4; ++r)
      rinv[m][r] = rsinv[m * 16 + ((lane >> 4) << 2) + r];

  char* ldsO = ldsP + wv * 8192;
  #pragma unroll
  for (int m = 0; m < 4; ++m)
    #pragma unroll
    for (int n = 0; n < 4; ++n)
      #pragma unroll
      for (int r = 0; r < 4; ++r) {
        int row = m * 16 + ((lane >> 4) << 2) + r;
        int col = n * 16 + (lane & 15);
        *(__hip_bfloat16*)(ldsO + row * 128 + col * 2) =
            __float2bfloat16(acc2[m][n][r] * rinv[m][r]);
      }
  __syncthreads();
  __hip_bfloat16* ob = Obuf + sbase + (size_t)w0 * HW + wv * 64;
  #pragma unroll
  for (int it = 0; it < 8; ++it) {
    int row = it * 8 + (lane >> 3);
    int c = (lane & 7) << 4;
    s16x8 v = *(const s16x8*)(ldsO + row * 128 + c);
    *(s16x8*)((char*)ob + (size_t)row * 1024 + c) = v;
  }
}

// ---------------------------------------------------------------------------
// Kernel 3: out[b][j][h][w] = sum_o wout[j][o] * O[b][o][w][h]
// ---------------------------------------------------------------------------
__global__ __launch_bounds__(256) void proj_kernel(
    const __hip_bfloat16* __restrict__ Obuf, const float* __restrict__ wout,
    float* __restrict__ out)
{
  const int b = blockIdx.y;
  const int t = blockIdx.x;
  const int h0 = (t >> 5) * 64;
  const int w0 = (t & 31) * 16;
  const int tid = threadIdx.x;
  __shared__ float os[8][16][65];
  __shared__ float wo_s[64];
  if (tid < 64) wo_s[tid] = wout[tid];
  {
    int r = tid >> 4;
    int c4 = (tid & 15) * 4;
    #pragma unroll
    for (int o = 0; o < 8; ++o) {
      const __hip_bfloat16* p = Obuf + ((size_t)(b * 8 + o) * HW + w0 + r) * HW + h0 + c4;
      u16x4 v = *(const u16x4*)p;
      #pragma unroll
      for (int i = 0; i < 4; ++i)
        os[o][r][c4 + i] = __uint_as_float((unsigned)v[i] << 16);
    }
  }
  __syncthreads();
  const int w = tid & 15;
  #pragma unroll
  for (int ih = 0; ih < 4; ++ih) {
    int h = ih * 16 + (tid >> 4);
    float ov[8];
    #pragma unroll
    for (int o = 0; o < 8; ++o) ov[o] = os[o][w][h];
    #pragma unroll
    for (int jo = 0; jo < 8; ++jo) {
      float a = 0.f;
      #pragma unroll
      for (int o = 0; o < 8; ++o) a += ov[o] * wo_s[jo * 8 + o];
      out[((size_t)(b * 8 + jo) * HW + h0 + h) * HW + w0 + w] = a;
    }
  }
}

extern "C" void kernel_launch(void* const* d_in, const int* in_sizes, int n_in,
                              void* d_out, int out_size, void* d_ws, size_t ws_size,
                              hipStream_t stream) {
  (void)in_sizes; (void)n_in; (void)out_size; (void)ws_size;
  const float* x    = (const float*)d_in[0];
  const float* wqkv = (const float*)d_in[1];
  const float* wdw  = (const float*)d_in[2];
  const float* wout = (const float*)d_in[3];
  const float* temp = (const float*)d_in[4];
  float* out = (float*)d_out;

  char* ws = (char*)d_ws;
  const size_t plane = (size_t)NSLICE * HW * HW * 2;  // 64 MiB bf16 plane
  __hip_bfloat16* qT = (__hip_bfloat16*)(ws);
  __hip_bfloat16* kT = (__hip_bfloat16*)(ws + plane);
  __hip_bfloat16* vS = (__hip_bfloat16*)(ws + 2 * plane);
  __hip_bfloat16* Ob = (__hip_bfloat16*)(ws + 3 * plane);
  float* qss = (float*)(ws + 4 * plane);
  float* kss = (float*)(ws + 4 * plane + (size_t)NSLICE * HW * 4);

  hipMemsetAsync(qss, 0, 2 * (size_t)NSLICE * HW * 4, stream);
  qkv_fused<<<dim3(256, 16), 256, 0, stream>>>(x, wqkv, wdw, qT, kT, vS, qss, kss);
  hipFuncSetAttribute((const void*)attn_kernel,
                      hipFuncAttributeMaxDynamicSharedMemorySize, ATTN_LDS_SIZE);
  attn_kernel<<<dim3(1024), 512, ATTN_LDS_SIZE, stream>>>(qT, kT, vS, Ob, qss, kss, temp);
  proj_kernel<<<dim3(256, 16), 256, 0, stream>>>(Ob, wout, out);
}